// Round 16
// baseline (392.907 us; speedup 1.0000x reference)
//
#include <hip/hip_runtime.h>
#include <hip/hip_bf16.h>

#define B_ 256
#define T_ 32
#define F_ 128
#define H_ 128
#define NF 64
#define OH 31
#define OW 255
#define POS_TOTAL (OH*OW)      // 7905
#define N1 256
#define KT 248                 // blocks = 31 y x 8 xb

typedef __attribute__((ext_vector_type(8))) short bf16x8;
typedef __attribute__((ext_vector_type(4))) float f32x4;

__device__ __forceinline__ unsigned int cvtpk(float lo, float hi) {
    unsigned int r;
    asm("v_cvt_pk_bf16_f32 %0, %1, %2" : "=v"(r) : "v"(lo), "v"(hi));
    return r;
}

// ---------------- K1: attention -> featL [b=256][rc=8192] ----------------
__global__ __launch_bounds__(256) void k_attn(
    const float* __restrict__ X, const float* __restrict__ W,
    const float* __restrict__ U, const float* __restrict__ V,
    float* __restrict__ featL)
{
    __shared__ float Xs[T_][F_];
    __shared__ float xw[T_][H_];
    __shared__ float xu[T_][H_];
    __shared__ float sc[T_][T_];
    __shared__ float Vs[H_];

    const int b = blockIdx.x;
    const int t = threadIdx.x;
    const float* Xb = X + (size_t)b * T_ * F_;

    for (int idx = t; idx < T_*F_; idx += 256) ((float*)Xs)[idx] = Xb[idx];
    if (t < H_) Vs[t] = V[t];
    __syncthreads();

    {
        const int h = t & 127, half = t >> 7;
        float aw[16], au[16];
        #pragma unroll
        for (int r = 0; r < 16; r++) { aw[r] = 0.f; au[r] = 0.f; }
        for (int f = 0; f < F_; f++) {
            const float wv = W[f*H_ + h];
            const float uv = U[f*H_ + h];
            #pragma unroll
            for (int r = 0; r < 16; r++) {
                const float xv = Xs[half*16 + r][f];
                aw[r] += xv * wv;
                au[r] += xv * uv;
            }
        }
        #pragma unroll
        for (int r = 0; r < 16; r++) {
            xw[half*16 + r][h] = aw[r];
            xu[half*16 + r][h] = au[r];
        }
    }
    __syncthreads();

    {
        const int i = t >> 3;
        const int j0 = (t & 7) * 4;
        float s0 = 0.f, s1 = 0.f, s2 = 0.f, s3 = 0.f;
        for (int h = 0; h < H_; h++) {
            const float xwv = xw[i][h];
            const float vv  = Vs[h];
            s0 += tanhf(xwv + xu[j0+0][h]) * vv;
            s1 += tanhf(xwv + xu[j0+1][h]) * vv;
            s2 += tanhf(xwv + xu[j0+2][h]) * vv;
            s3 += tanhf(xwv + xu[j0+3][h]) * vv;
        }
        sc[i][j0+0] = s0; sc[i][j0+1] = s1; sc[i][j0+2] = s2; sc[i][j0+3] = s3;
    }
    __syncthreads();

    if (t < T_) {
        float m = -1e30f;
        #pragma unroll
        for (int j = 0; j < T_; j++) m = fmaxf(m, sc[t][j]);
        float sum = 0.f;
        #pragma unroll
        for (int j = 0; j < T_; j++) sum += expf(sc[t][j] - m);
        const float inv = 1.f / sum;
        #pragma unroll
        for (int j = 0; j < T_; j++) {
            const float a = expf(sc[t][j] - m) * inv;
            sc[t][j] = (j == t) ? 0.f : a;
        }
    }
    __syncthreads();

    for (int idx = t; idx < T_*F_; idx += 256) {
        const int row = idx >> 7, f = idx & 127;
        float acc = 0.f;
        #pragma unroll
        for (int j = 0; j < T_; j++) acc += sc[row][j] * Xs[j][f];
        float* fr = featL + (size_t)b*8192 + row*256;
        fr[f]       = Xs[row][f];
        fr[128 + f] = acc;
    }
}

// -------- K1b: transpose featL[b][rc] -> featT[rc][b], LDS-tiled --------
__global__ __launch_bounds__(256) void k_tr(
    const float* __restrict__ src, float* __restrict__ dst)
{
    __shared__ float tile[32][33];
    const int rc0 = blockIdx.x * 32;
    const int b0  = blockIdx.y * 32;
    const int tx = threadIdx.x & 31;
    const int ty = threadIdx.x >> 5;
    #pragma unroll
    for (int r = 0; r < 32; r += 8)
        tile[ty + r][tx] = src[(size_t)(b0 + ty + r)*8192 + rc0 + tx];
    __syncthreads();
    #pragma unroll
    for (int r = 0; r < 32; r += 8)
        dst[(size_t)(rc0 + ty + r)*256 + b0 + tx] = tile[tx][ty + r];
}

// ------- K2: fused conv + MFMA GEMM1 — R11 base, static dual-set pipeline -------
// Grid 248 = (y = kt>>3, xb = kt&7). Tile 256x256, 32 steps of K=64 (2 filters
// x 32 pos). W: float4 loads into TWO register sets, static refill distance 2
// (all set names / buffer indices compile-time). As/Ws 2 x 32 KiB, XOR swizzle.
// lgkm-only barriers. Waves 2m x 4n (wave tile 128x64).
__global__ __launch_bounds__(512, 2) void k_gemm1(
    const float* __restrict__ featT, const float* __restrict__ cw,
    const float* __restrict__ cb, const float* __restrict__ w1,
    float* __restrict__ partial)
{
    __shared__ unsigned short As[2][256*64];   // 2 x 32 KiB
    __shared__ unsigned short Ws[2][256*64];   // 2 x 32 KiB
    __shared__ float cwL[256];
    __shared__ float cbL[64];

    const int t  = threadIdx.x;
    const int kt = blockIdx.x;
    const int y  = kt >> 3;
    const int x0 = (kt & 7) * 32;

    if (t < 256) cwL[t] = cw[t];
    if (t < 64)  cbL[t] = cb[t];

    // A-staging role: row rm, pos-half ph (16 pos each)
    const int rm = t & 255;
    const int ph = t >> 8;
    // W-staging role: 4 k-rows x 8 n-cols
    const int r0 = (t & 15) * 4;        // k-local 0..60
    const int c0 = (t >> 4) * 8;        // n 0..248
    // MFMA role: 8 waves = 2(m) x 4(n); wave tile 128x64
    const int lane = t & 63, wid = t >> 6;
    const int wm = (wid >> 2) * 128;
    const int wn = (wid & 3) * 64;
    const int fr = lane & 15, fq = lane >> 4;

    f32x4 acc[8][4];
    #pragma unroll
    for (int i = 0; i < 8; i++)
        #pragma unroll
        for (int j = 0; j < 4; j++)
            acc[i][j] = (f32x4){0.f, 0.f, 0.f, 0.f};

    // ---- block-constant conv patch: overlapping taps -> 2x17 regs ----
    float topv[17], botv[17];
    #pragma unroll
    for (int i = 0; i < 17; i++) {
        int xc = x0 + ph*16 + i; if (xc > 255) xc = 255;
        topv[i] = featT[((size_t)(y*256 + xc))*256 + rm];
        botv[i] = featT[((size_t)((y+1)*256 + xc))*256 + rm];
    }

    float wvA[4][8], wvB[4][8];   // two pipelined W sets: [k-row jj][n-col i]

    // W loads for step S into DST: rows r0..r0+3 (k-local), cols c0..c0+7
#define W_LOADS(DST, S)                                                        \
    {                                                                          \
        const int fl_ = r0 >> 5;                                               \
        const int f_  = 2*(S) + fl_;                                           \
        _Pragma("unroll")                                                      \
        for (int jj = 0; jj < 4; jj++) {                                       \
            int xc_ = x0 + (r0 & 31) + jj; if (xc_ > 254) xc_ = 254;           \
            const float* wp_ = w1 + ((size_t)(f_*POS_TOTAL + y*255 + xc_))*N1  \
                                  + c0;                                        \
            *(float4*)&DST[jj][0] = *(const float4*)&wp_[0];                   \
            *(float4*)&DST[jj][4] = *(const float4*)&wp_[4];                   \
        }                                                                      \
    }

    // stage step S into buffer BUF: W transpose-write (from WSRC) + conv A
#define STAGE(BUF, S, WSRC)                                                    \
    {                                                                          \
        _Pragma("unroll")                                                      \
        for (int i = 0; i < 8; i++) {                                          \
            const int n_ = c0 + i;                                             \
            uint2 v_;                                                          \
            v_.x = cvtpk(WSRC[0][i], WSRC[1][i]);                              \
            v_.y = cvtpk(WSRC[2][i], WSRC[3][i]);                              \
            const int blk_ = (r0 >> 3) ^ (n_ & 7);                             \
            *(uint2*)&Ws[BUF][n_*64 + blk_*8 + (r0 & 7)] = v_;                 \
        }                                                                      \
        _Pragma("unroll")                                                      \
        for (int fl = 0; fl < 2; fl++) {                                       \
            const int f_ = 2*(S) + fl;                                         \
            const float4 cc_ = *(const float4*)&cwL[f_*4];                     \
            const float cbv_ = cbL[f_];                                        \
            unsigned int pk_[4];                                               \
            _Pragma("unroll")                                                  \
            for (int i2 = 0; i2 < 8; i2++) {                                   \
                const int i0 = 2*i2, i1 = 2*i2 + 1;                            \
                float v0_ = topv[i0]*cc_.x + topv[i0+1]*cc_.y                  \
                          + botv[i0]*cc_.z + botv[i0+1]*cc_.w + cbv_;          \
                float v1_ = topv[i1]*cc_.x + topv[i1+1]*cc_.y                  \
                          + botv[i1]*cc_.z + botv[i1+1]*cc_.w + cbv_;          \
                v0_ = (x0 + ph*16 + i0 < 255) ? fmaxf(v0_, 0.f) : 0.f;         \
                v1_ = (x0 + ph*16 + i1 < 255) ? fmaxf(v1_, 0.f) : 0.f;         \
                pk_[i2 & 3] = cvtpk(v0_, v1_);                                 \
                if ((i2 & 3) == 3) {                                           \
                    const int kb_ = fl*4 + ph*2 + (i2 >> 2);                   \
                    *(uint4*)&As[BUF][rm*64 + ((kb_ ^ (rm & 7))*8)]            \
                        = *(uint4*)&pk_[0];                                    \
                }                                                              \
            }                                                                  \
        }                                                                      \
    }

#define DO_MFMA(BUF)                                                           \
    {                                                                          \
        __builtin_amdgcn_s_setprio(1);                                         \
        _Pragma("unroll")                                                      \
        for (int kc = 0; kc < 2; kc++) {                                       \
            const int sw = ((kc*4 + fq) ^ (fr & 7)) * 8;                       \
            bf16x8 bf_[4];                                                     \
            _Pragma("unroll")                                                  \
            for (int ng = 0; ng < 4; ng++)                                     \
                bf_[ng] = *(const bf16x8*)&Ws[BUF][(wn + ng*16 + fr)*64 + sw]; \
            _Pragma("unroll")                                                  \
            for (int mg = 0; mg < 8; mg++) {                                   \
                const bf16x8 af_ =                                             \
                    *(const bf16x8*)&As[BUF][(wm + mg*16 + fr)*64 + sw];       \
                _Pragma("unroll")                                              \
                for (int ng = 0; ng < 4; ng++)                                 \
                    acc[mg][ng] = __builtin_amdgcn_mfma_f32_16x16x32_bf16(     \
                        af_, bf_[ng], acc[mg][ng], 0, 0, 0);                   \
            }                                                                  \
        }                                                                      \
        __builtin_amdgcn_s_setprio(0);                                         \
    }

#define LB() do { asm volatile("s_waitcnt lgkmcnt(0)" ::: "memory"); \
                  __builtin_amdgcn_s_barrier(); } while (0)

    // ---- prologue ----
    W_LOADS(wvA, 0);
    W_LOADS(wvB, 1);
    __syncthreads();             // one-time full drain: cwL/cbL/patch/wvA/wvB
    STAGE(0, 0, wvA);
    W_LOADS(wvA, 2);             // refill for step 2 (distance 2)
    LB();

    // ---- steady state: 2 steps/iter, all indices static ----
    #pragma unroll 1
    for (int g = 0; g < 15; g++) {
        const int S = 2*g;
        STAGE(1, S+1, wvB);              // consume wvB = W(S+1), 2-step-old
        W_LOADS(wvB, S+3);               // refill; consumed next iter
        DO_MFMA(0);                      // step S
        LB();
        STAGE(0, S+2, wvA);              // consume wvA = W(S+2), 2-step-old
        if (g < 14) W_LOADS(wvA, S+4);   // refill; consumed next iter
        DO_MFMA(1);                      // step S+1
        LB();
    }
    // ---- epilogue: steps 30, 31 ----
    STAGE(1, 31, wvB);
    DO_MFMA(0);                          // step 30
    LB();
    DO_MFMA(1);                          // step 31

    // ---- write fp32 partial tile (256x256) ----
    float* pp = partial + (size_t)kt * (256*N1);
    #pragma unroll
    for (int mg = 0; mg < 8; mg++)
        #pragma unroll
        for (int ng = 0; ng < 4; ng++) {
            const int col = wn + ng*16 + fr;
            #pragma unroll
            for (int j = 0; j < 4; j++) {
                const int row = wm + mg*16 + fq*4 + j;
                pp[(size_t)row*N1 + col] = acc[mg][ng][j];
            }
        }
#undef W_LOADS
#undef STAGE
#undef DO_MFMA
#undef LB
}

// ------- K3: reduce partials + b1/relu + h@w2 relu + @w3 + b3 -------
__global__ __launch_bounds__(256) void k_head(
    const float* __restrict__ partial,
    const float* __restrict__ b1, const float* __restrict__ w2,
    const float* __restrict__ b2, const float* __restrict__ w3,
    const float* __restrict__ b3, float* __restrict__ out)
{
    __shared__ float h1s[256];
    __shared__ float h2s[32];
    const int b = blockIdx.x, t = threadIdx.x;

    const float* pb = partial + (size_t)b*N1 + t;
    float s0 = 0.f, s1 = 0.f, s2 = 0.f, s3 = 0.f;
    #pragma unroll 2
    for (int kt = 0; kt < KT; kt += 4) {
        s0 += pb[(size_t)(kt+0)*65536];
        s1 += pb[(size_t)(kt+1)*65536];
        s2 += pb[(size_t)(kt+2)*65536];
        s3 += pb[(size_t)(kt+3)*65536];
    }
    h1s[t] = fmaxf(b1[t] + ((s0+s1)+(s2+s3)), 0.f);
    __syncthreads();

    if (t < 32) {
        float s2v = b2[t];
        for (int i = 0; i < 256; i++) s2v += h1s[i] * w2[i*32 + t];
        h2s[t] = fmaxf(s2v, 0.f);
    }
    __syncthreads();

    if (t < 2) {
        float s3v = b3[t];
        #pragma unroll
        for (int i = 0; i < 32; i++) s3v += h2s[i] * w3[i*2 + t];
        out[b*2 + t] = s3v;
    }
}

extern "C" void kernel_launch(void* const* d_in, const int* in_sizes, int n_in,
                              void* d_out, int out_size, void* d_ws, size_t ws_size,
                              hipStream_t stream) {
    const float* X    = (const float*)d_in[0];
    const float* attW = (const float*)d_in[1];
    const float* attU = (const float*)d_in[2];
    const float* attV = (const float*)d_in[3];
    const float* cw   = (const float*)d_in[4];
    const float* cb   = (const float*)d_in[5];
    const float* w1   = (const float*)d_in[6];
    const float* b1   = (const float*)d_in[7];
    const float* w2   = (const float*)d_in[8];
    const float* b2   = (const float*)d_in[9];
    const float* w3   = (const float*)d_in[10];
    const float* b3   = (const float*)d_in[11];
    float* out = (float*)d_out;

    float* featL   = (float*)d_ws;                                   //  8 MB
    float* featT   = (float*)((char*)d_ws + (8u<<20));               //  8 MB
    float* partial = (float*)((char*)d_ws + (16u<<20));              // 62 MB

    k_attn <<<dim3(B_),       dim3(256), 0, stream>>>(X, attW, attU, attV, featL);
    k_tr   <<<dim3(256, 8),   dim3(256), 0, stream>>>(featL, featT);
    k_gemm1<<<dim3(KT),       dim3(512), 0, stream>>>(featT, cw, cb, w1, partial);
    k_head <<<dim3(B_),       dim3(256), 0, stream>>>(partial, b1, w2, b2, w3, b3, out);
}